// Round 1
// baseline (5251.836 us; speedup 1.0000x reference)
//
#include <hip/hip_runtime.h>
#include <hip/hip_bf16.h>
#include <stdint.h>

// Problem constants
#define S_INPUT  1024
#define S_HIDDEN 2048
#define S_SEQ    256
#define S_BATCH  256

typedef __attribute__((ext_vector_type(8))) short bf16x8;   // 8 bf16 = 4 VGPRs
typedef __attribute__((ext_vector_type(4))) float f32x4;    // MFMA accumulator

__device__ __forceinline__ short f2bf(float f){
  union { float f; unsigned u; } v; v.f = f;
  unsigned r = v.u + 0x7fffu + ((v.u >> 16) & 1u);   // round-nearest-even
  return (short)(r >> 16);
}

// ---------------------------------------------------------------------------
// 64x64x(K) bf16 GEMM core, B^T layout: out[m][n] = sum_k A[m][k]*B[n][k].
// 256 threads = 4 waves in 2x2 grid, each wave owns a 32x32 sub-tile.
// global_load_lds(16B) staging, linear LDS dest + inverse-swizzled global
// source + swizzled ds_read (XOR bits 4-6 with row&7) to kill the 32-way
// bank conflict of 128B-stride rows.
// ---------------------------------------------------------------------------
__device__ __forceinline__ void stage_pair(const short* __restrict__ Ab, int lda,
                                           const short* __restrict__ Bb, int ldb,
                                           int kt, char* As, char* Bs, int tid)
{
  #pragma unroll
  for (int it = 0; it < 2; ++it){
    int c    = tid + it*256;            // 512 chunks of 16B per 8KB tile
    int row  = c >> 3;                  // 8 chunks per 128B row
    int colB = ((c & 7) << 4) ^ ((row & 7) << 4);   // inverse swizzle on source
    const short* sa = Ab + (size_t)row*lda + kt*64 + (colB >> 1);
    const short* sb = Bb + (size_t)row*ldb + kt*64 + (colB >> 1);
    __builtin_amdgcn_global_load_lds((__attribute__((address_space(1))) void*)sa,
                                     (__attribute__((address_space(3))) void*)(As + c*16), 16, 0, 0);
    __builtin_amdgcn_global_load_lds((__attribute__((address_space(1))) void*)sb,
                                     (__attribute__((address_space(3))) void*)(Bs + c*16), 16, 0, 0);
  }
}

__device__ __forceinline__ void gemm_core(const short* __restrict__ A, int lda,
                                          const short* __restrict__ B, int ldb,
                                          int bm, int bn, int ktiles,
                                          f32x4 acc[2][2], char* As, char* Bs)
{
  const int tid  = threadIdx.x;
  const int lane = tid & 63;
  const int wid  = tid >> 6;
  const int wm   = (wid >> 1) & 1;
  const int wn   = wid & 1;
  const int r15  = lane & 15;
  const int hi   = lane >> 4;

  const short* Ab = A + (size_t)bm*lda;
  const short* Bb = B + (size_t)bn*ldb;

  const int ra0 = wm*32 + r15,  ra1 = ra0 + 16;
  const int rb0 = wn*32 + r15,  rb1 = rb0 + 16;

  for (int kt = 0; kt < ktiles; ++kt){
    __syncthreads();                       // LDS reuse: previous reads done
    stage_pair(Ab, lda, Bb, ldb, kt, As, Bs, tid);
    asm volatile("s_waitcnt vmcnt(0)" ::: "memory");
    __syncthreads();                       // tile visible to all waves
    #pragma unroll
    for (int kk = 0; kk < 2; ++kk){
      const int kb = kk*64 + hi*16;        // byte col offset within 128B row
      bf16x8 a0 = *(const bf16x8*)(As + (ra0*128 + (kb ^ ((ra0 & 7) << 4))));
      bf16x8 a1 = *(const bf16x8*)(As + (ra1*128 + (kb ^ ((ra1 & 7) << 4))));
      bf16x8 b0 = *(const bf16x8*)(Bs + (rb0*128 + (kb ^ ((rb0 & 7) << 4))));
      bf16x8 b1 = *(const bf16x8*)(Bs + (rb1*128 + (kb ^ ((rb1 & 7) << 4))));
      acc[0][0] = __builtin_amdgcn_mfma_f32_16x16x32_bf16(a0, b0, acc[0][0], 0, 0, 0);
      acc[0][1] = __builtin_amdgcn_mfma_f32_16x16x32_bf16(a0, b1, acc[0][1], 0, 0, 0);
      acc[1][0] = __builtin_amdgcn_mfma_f32_16x16x32_bf16(a1, b0, acc[1][0], 0, 0, 0);
      acc[1][1] = __builtin_amdgcn_mfma_f32_16x16x32_bf16(a1, b1, acc[1][1], 0, 0, 0);
    }
  }
}

// C/D layout (m89-verified): within a 16x16 frag, col = lane&15, row = (lane>>4)*4 + i.
#define EPI_COORDS \
  const int lane = threadIdx.x & 63, wid = threadIdx.x >> 6; \
  const int wm = (wid>>1)&1, wn = wid&1, r15 = lane&15, hi = lane>>4;

// ---------------------------------------------------------------------------
// Prologue kernels
// ---------------------------------------------------------------------------
// Wcat[j][0:1024] = bf16(W_ih[j]), Wcat[j][1024:3072] = bf16(W_hh[j])
__global__ __launch_bounds__(256) void k_build_wcat(const float* __restrict__ Wih,
                                                    const float* __restrict__ Whh,
                                                    short* __restrict__ Wcat)
{
  int j = blockIdx.x;
  for (int i = threadIdx.x; i < 3072; i += 256){
    float f = (i < 1024) ? Wih[(size_t)j*1024 + i] : Whh[(size_t)j*2048 + (i-1024)];
    Wcat[(size_t)j*3072 + i] = f2bf(f);
  }
}

// Acat[b][0:1024] = bf16(x0[b]), Acat[b][1024:3072] = bf16(h0[b])
__global__ __launch_bounds__(256) void k_build_acat(const float* __restrict__ x,
                                                    const float* __restrict__ h0,
                                                    short* __restrict__ Acat)
{
  int b = blockIdx.x;
  for (int i = threadIdx.x; i < 3072; i += 256){
    float f = (i < 1024) ? x[(size_t)b*1024 + i] : h0[(size_t)b*2048 + (i-1024)];
    Acat[(size_t)b*3072 + i] = f2bf(f);
  }
}

// Wfcb[i][k] = bf16(W_fc[i][k]) ; WfcT[k][i] = bf16(W_fc[i][k])
__global__ __launch_bounds__(256) void k_trans_wfc(const float* __restrict__ Wfc,
                                                   short* __restrict__ Wfcb,
                                                   short* __restrict__ WfcT)
{
  __shared__ float t[32][33];
  int i0 = blockIdx.x*32, k0 = blockIdx.y*32;
  int c = threadIdx.x & 31, r = threadIdx.x >> 5;   // r in 0..7
  #pragma unroll
  for (int rr = 0; rr < 4; ++rr){
    int i = i0 + r*4 + rr, k = k0 + c;
    float v = Wfc[(size_t)i*2048 + k];
    Wfcb[(size_t)i*2048 + k] = f2bf(v);
    t[r*4+rr][c] = v;
  }
  __syncthreads();
  #pragma unroll
  for (int rr = 0; rr < 4; ++rr){
    int k = k0 + r*4 + rr, i = i0 + c;
    WfcT[(size_t)k*1024 + i] = f2bf(t[c][r*4+rr]);
  }
}

// brnn[j] = b_ih[j]+b_hh[j] ; cvec[j] = brnn[j] + sum_i W_ih[j][i]*b_fc[i]
__global__ __launch_bounds__(256) void k_cvec(const float* __restrict__ Wih,
                                              const float* __restrict__ bfc,
                                              const float* __restrict__ bih,
                                              const float* __restrict__ bhh,
                                              float* __restrict__ brnn,
                                              float* __restrict__ cvec)
{
  __shared__ float red[256];
  int j = blockIdx.x;
  float s = 0.f;
  for (int i = threadIdx.x; i < 1024; i += 256) s += Wih[(size_t)j*1024 + i]*bfc[i];
  red[threadIdx.x] = s; __syncthreads();
  for (int st = 128; st > 0; st >>= 1){
    if (threadIdx.x < st) red[threadIdx.x] += red[threadIdx.x+st];
    __syncthreads();
  }
  if (threadIdx.x == 0){
    float br = bih[j] + bhh[j];
    brnn[j] = br;
    cvec[j] = br + red[0];
  }
}

// Wcomb[j][k] = bf16( sum_i W_ih[j][i]*W_fc[i][k] + W_hh[j][k] )
__global__ __launch_bounds__(256) void k_wcomb(const short* __restrict__ Wcat,
                                               const short* __restrict__ WfcT,
                                               const float* __restrict__ Whh,
                                               short* __restrict__ Wcomb)
{
  __shared__ char As[8192], Bs[8192];
  f32x4 acc[2][2] = {};
  int bm = (blockIdx.x >> 5) * 64, bn = (blockIdx.x & 31) * 64;
  gemm_core(Wcat, 3072, WfcT, 1024, bm, bn, 16, acc, As, Bs);
  EPI_COORDS
  #pragma unroll
  for (int mi = 0; mi < 2; ++mi)
    #pragma unroll
    for (int ni = 0; ni < 2; ++ni){
      int n = bn + wn*32 + ni*16 + r15;
      #pragma unroll
      for (int i = 0; i < 4; ++i){
        int m = bm + wm*32 + mi*16 + hi*4 + i;
        Wcomb[(size_t)m*2048 + n] = f2bf(acc[mi][ni][i] + Whh[(size_t)m*2048 + n]);
      }
    }
}

// h1 = tanh(Acat @ Wcat^T + brnn)
__global__ __launch_bounds__(256) void k_h1(const short* __restrict__ Acat,
                                            const short* __restrict__ Wcat,
                                            const float* __restrict__ brnn,
                                            short* __restrict__ h1)
{
  __shared__ char As[8192], Bs[8192];
  f32x4 acc[2][2] = {};
  int bm = (blockIdx.x >> 5) * 64, bn = (blockIdx.x & 31) * 64;
  gemm_core(Acat, 3072, Wcat, 3072, bm, bn, 48, acc, As, Bs);
  EPI_COORDS
  #pragma unroll
  for (int mi = 0; mi < 2; ++mi)
    #pragma unroll
    for (int ni = 0; ni < 2; ++ni){
      int n = bn + wn*32 + ni*16 + r15;
      float cb = brnn[n];
      #pragma unroll
      for (int i = 0; i < 4; ++i){
        int m = bm + wm*32 + mi*16 + hi*4 + i;
        h1[(size_t)m*2048 + n] = f2bf(tanhf(acc[mi][ni][i] + cb));
      }
    }
}

// Fused step: blocks 0..127: h_{t+1} = tanh(h_t @ Wcomb^T + cvec)  (bf16 out)
//             blocks 128..191: out_{t-1} = h_t @ Wfc^T + b_fc      (f32 -> d_out)
__global__ __launch_bounds__(256) void k_step(const short* __restrict__ hcur,
                                              const short* __restrict__ Wcomb,
                                              const float* __restrict__ cvec,
                                              short* __restrict__ hnext,
                                              const short* __restrict__ Wfcb,
                                              const float* __restrict__ bfc,
                                              float* __restrict__ outp)
{
  __shared__ char As[8192], Bs[8192];
  f32x4 acc[2][2] = {};
  int bid = blockIdx.x;
  if (bid < 128){
    int bm = (bid >> 5) * 64, bn = (bid & 31) * 64;
    gemm_core(hcur, S_HIDDEN, Wcomb, S_HIDDEN, bm, bn, 32, acc, As, Bs);
    EPI_COORDS
    #pragma unroll
    for (int mi = 0; mi < 2; ++mi)
      #pragma unroll
      for (int ni = 0; ni < 2; ++ni){
        int n = bn + wn*32 + ni*16 + r15;
        float cb = cvec[n];
        #pragma unroll
        for (int i = 0; i < 4; ++i){
          int m = bm + wm*32 + mi*16 + hi*4 + i;
          hnext[(size_t)m*S_HIDDEN + n] = f2bf(tanhf(acc[mi][ni][i] + cb));
        }
      }
  } else {
    int b2 = bid - 128;
    int bm = (b2 >> 4) * 64, bn = (b2 & 15) * 64;
    gemm_core(hcur, S_HIDDEN, Wfcb, S_HIDDEN, bm, bn, 32, acc, As, Bs);
    EPI_COORDS
    #pragma unroll
    for (int mi = 0; mi < 2; ++mi)
      #pragma unroll
      for (int ni = 0; ni < 2; ++ni){
        int n = bn + wn*32 + ni*16 + r15;
        float cb = bfc[n];
        #pragma unroll
        for (int i = 0; i < 4; ++i){
          int m = bm + wm*32 + mi*16 + hi*4 + i;
          outp[(size_t)m*(S_SEQ*S_INPUT) + n] = acc[mi][ni][i] + cb;
        }
      }
  }
}

// out_255 = h_256 @ Wfc^T + b_fc
__global__ __launch_bounds__(256) void k_final(const short* __restrict__ hcur,
                                               const short* __restrict__ Wfcb,
                                               const float* __restrict__ bfc,
                                               float* __restrict__ outp)
{
  __shared__ char As[8192], Bs[8192];
  f32x4 acc[2][2] = {};
  int bm = (blockIdx.x >> 4) * 64, bn = (blockIdx.x & 15) * 64;
  gemm_core(hcur, S_HIDDEN, Wfcb, S_HIDDEN, bm, bn, 32, acc, As, Bs);
  EPI_COORDS
  #pragma unroll
  for (int mi = 0; mi < 2; ++mi)
    #pragma unroll
    for (int ni = 0; ni < 2; ++ni){
      int n = bn + wn*32 + ni*16 + r15;
      float cb = bfc[n];
      #pragma unroll
      for (int i = 0; i < 4; ++i){
        int m = bm + wm*32 + mi*16 + hi*4 + i;
        outp[(size_t)m*(S_SEQ*S_INPUT) + n] = acc[mi][ni][i] + cb;
      }
    }
}

// ---------------------------------------------------------------------------
extern "C" void kernel_launch(void* const* d_in, const int* in_sizes, int n_in,
                              void* d_out, int out_size, void* d_ws, size_t ws_size,
                              hipStream_t stream)
{
  const float* x   = (const float*)d_in[0];   // (256,1,1024)
  const float* h0  = (const float*)d_in[1];   // (1,256,2048)
  const float* Wih = (const float*)d_in[2];   // (2048,1024)
  const float* Whh = (const float*)d_in[3];   // (2048,2048)
  const float* bih = (const float*)d_in[4];   // (2048)
  const float* bhh = (const float*)d_in[5];   // (2048)
  const float* Wfc = (const float*)d_in[6];   // (1024,2048)
  const float* bfc = (const float*)d_in[7];   // (1024)
  float* out = (float*)d_out;                 // (256,256,1024) f32

  char* ws = (char*)d_ws;
  size_t off = 0;
  auto alloc = [&](size_t bytes) -> void* {
    void* p = ws + off;
    off += (bytes + 255) & ~(size_t)255;
    return p;
  };
  short* Wcat = (short*)alloc((size_t)2048*3072*2);   // [W_ih | W_hh] bf16
  short* Acat = (short*)alloc((size_t)256*3072*2);    // [x0 | h0] bf16
  short* WfcT = (short*)alloc((size_t)2048*1024*2);   // W_fc^T bf16
  short* Wfcb = (short*)alloc((size_t)1024*2048*2);   // W_fc bf16
  short* Wcb  = (short*)alloc((size_t)2048*2048*2);   // Wcomb bf16
  short* hb0  = (short*)alloc((size_t)256*2048*2);
  short* hb1  = (short*)alloc((size_t)256*2048*2);
  float* brnn = (float*)alloc(2048*4);
  float* cvec = (float*)alloc(2048*4);
  (void)ws_size; (void)in_sizes; (void)n_in; (void)out_size;

  // Prologue
  k_build_wcat<<<2048, 256, 0, stream>>>(Wih, Whh, Wcat);
  k_build_acat<<<256, 256, 0, stream>>>(x, h0, Acat);
  k_trans_wfc<<<dim3(32, 64), 256, 0, stream>>>(Wfc, Wfcb, WfcT);
  k_cvec<<<2048, 256, 0, stream>>>(Wih, bfc, bih, bhh, brnn, cvec);
  k_wcomb<<<1024, 256, 0, stream>>>(Wcat, WfcT, Whh, Wcb);
  k_h1<<<128, 256, 0, stream>>>(Acat, Wcat, brnn, hb0);

  // Sequential steps: launch t computes h_{t+1} (task A) and out_{t-1} (task B)
  short* h[2] = { hb0, hb1 };
  int cur = 0;
  for (int t = 1; t <= 255; ++t){
    k_step<<<192, 256, 0, stream>>>(h[cur], Wcb, cvec, h[cur^1], Wfcb, bfc,
                                    out + (size_t)(t-1)*S_INPUT);
    cur ^= 1;
  }
  k_final<<<64, 256, 0, stream>>>(h[cur], Wfcb, bfc, out + (size_t)255*S_INPUT);
}